// Round 1
// 1238.359 us; speedup vs baseline: 1.0712x; 1.0712x over previous
//
#include <hip/hip_runtime.h>
#include <stdint.h>

// LTC encoder B=256,T=1024,F=64,H=128. One WG per batch row.
// R9: MFMA-GEMV restructure. 16 waves (1024 thr): waves 0-7 = layer0 step t
// (16 cols each), waves 8-15 = layer1 step t-1. Per-step dots moved from
// v_dot2 chains (VALU, 45% busy / measured bottleneck) to the idle matrix
// pipe (MfmaUtil was 0) via mfma_f32_16x16x32_f16 with broadcast-A:
// every lane loads the same h-fragment -> all 16 A-rows identical -> acc[0]
// of every lane = dot(h, W[col]) for col = lane&15. Consistent k-packing of
// A (our LDS format) and B (our register pre-pack) makes this robust to the
// exact HW k-layout; only C/D layout is relied on (col=lane&15, verified).
// f16 kept (not bf16) for precision parity with R8 (absmax 0.0469).
// Occupancy 2 -> 4 waves/SIMD hides the barrier/LDS stalls (was ~55% stall).

#define B_ 256
#define T_ 1024
#define F_ 64
#define H_ 128
#define EPS_ 1e-5f
#define NT_ 1024

typedef _Float16 h2 __attribute__((ext_vector_type(2)));
typedef _Float16 h8 __attribute__((ext_vector_type(8)));
typedef float f32x4 __attribute__((ext_vector_type(4)));
typedef __fp16  f16v2 __attribute__((ext_vector_type(2)));

__device__ __forceinline__ h2 pkf16(float a, float b) {
  union { f16v2 f; h2 h; } c;
  c.f = __builtin_amdgcn_cvt_pkrtz(a, b);
  return c.h;
}
__device__ __forceinline__ uint32_t as_u32(h2 h) { union { h2 h; uint32_t u; } c; c.h = h; return c.u; }

// pack 8 consecutive fp32 weights into one MFMA half-fragment (4 VGPRs)
__device__ __forceinline__ h8 packfrag(const float* p) {
  float4 a = *(const float4*)p;
  float4 b = *(const float4*)(p + 4);
  union { h2 h[4]; h8 v; } c;
  c.h[0] = pkf16(a.x, a.y); c.h[1] = pkf16(a.z, a.w);
  c.h[2] = pkf16(b.x, b.y); c.h[3] = pkf16(b.z, b.w);
  return c.v;
}
// broadcast A-fragment from packed-f16 LDS (16B, wave-broadcast, conflict-free)
__device__ __forceinline__ h8 ldfrag(const uint32_t* p) {
  union { uint4 u; h8 v; } c;
  c.u = *(const uint4*)p;
  return c.v;
}

__device__ __forceinline__ float tanh_fast(float a) {
  float aa = fabsf(a);
  float e  = __expf(2.f * aa);
  float th = 1.f - 2.f / (e + 1.f);
  return copysignf(th, a);
}
__device__ __forceinline__ float softplus_fast(float x) {
  return (x > 20.f) ? x : __logf(1.f + __expf(x));
}

// cell math + LN. Per lane: one column (col = tile*16 + (l&15)); 4 lane-groups
// (l>>4) hold identical copies. Stats: 4-level DPP butterfly over lane&15
// (16 distinct cols per wave) + 8-wave LDS partial combine. 2 barriers.
__device__ __forceinline__ float ln_tail2(
    float pa, float pt, float hold,
    float bhx, float btr, float taub, float gr, float ber,
    int l, int wid, float2* part, int pbase,
    uint32_t* dstp, int widx, bool we)
{
  float f   = tanh_fast(pa + bhx);
  float tau = taub + softplus_fast(pt + btr);
  float hc  = fmaf(f - hold, __builtin_amdgcn_rcpf(tau), hold);
  float s = hc, s2 = hc * hc;
  s += __shfl_xor(s, 1); s2 += __shfl_xor(s2, 1);
  s += __shfl_xor(s, 2); s2 += __shfl_xor(s2, 2);
  s += __shfl_xor(s, 4); s2 += __shfl_xor(s2, 4);
  s += __shfl_xor(s, 8); s2 += __shfl_xor(s2, 8);
  if (l == 0) part[wid] = make_float2(s, s2);
  __syncthreads();                                   // barrier 1
  const float4* pp = (const float4*)(part + pbase);
  float4 q0 = pp[0], q1 = pp[1], q2 = pp[2], q3 = pp[3];
  float ss  = q0.x + q0.z + q1.x + q1.z + q2.x + q2.z + q3.x + q3.z;
  float s22 = q0.y + q0.w + q1.y + q1.w + q2.y + q2.w + q3.y + q3.w;
  float mu = ss * (1.f / 128.f);
  float m2 = s22 * (1.f / 128.f);
  float rstd = rsqrtf(m2 - mu * mu + EPS_);
  float hn = fmaf((hc - mu) * rstd, gr, ber);
  // pack cols (c, c+1): partner col's hn is in lane l+1
  float hn2 = __shfl_down(hn, 1);
  if (we && (l & 49) == 0) dstp[widx] = as_u32(pkf16(hn, hn2));  // g==0, even col
  __syncthreads();                                   // barrier 2
  return hn;
}

__global__ void __attribute__((amdgpu_flat_work_group_size(NT_, NT_)))
ltc_scan(
    const float* __restrict__ x,
    const float* __restrict__ Wh0, const float* __restrict__ bh0,
    const float* __restrict__ Wx0, const float* __restrict__ bx0,
    const float* __restrict__ Wt0, const float* __restrict__ bt0,
    const float* __restrict__ tau0, const float* __restrict__ g0,
    const float* __restrict__ be0,
    const float* __restrict__ Wh1, const float* __restrict__ bh1,
    const float* __restrict__ Wx1, const float* __restrict__ bx1,
    const float* __restrict__ Wt1, const float* __restrict__ bt1,
    const float* __restrict__ tau1, const float* __restrict__ g1,
    const float* __restrict__ be1,
    float* __restrict__ out)
{
  __shared__ __align__(16) uint32_t h0p[2][64];   // h0 packed f16 pairs, dbuf
  __shared__ __align__(16) uint32_t h1p[64];      // h1 packed
  __shared__ __align__(16) uint32_t x3[3][32];    // x[t] packed f16, 3-ring
  __shared__ __align__(16) float2   part[16];

  const int tid = threadIdx.x;
  const int wid = tid >> 6;
  const int l   = tid & 63;
  const int g4  = (l >> 4) << 2;    // LDS u32 offset of this lane-group's frag
  const int cl  = l & 15;
  const int b   = blockIdx.x;
  const float* xg = x + (size_t)b * (T_ * F_);

  if (tid < 64) { h0p[0][tid] = 0u; h0p[1][tid] = 0u; h1p[tid] = 0u; }
  if (tid < 32) {                   // stage x[0], x[1]
    float2 a = *(const float2*)(xg + 2 * tid);
    float2 c = *(const float2*)(xg + F_ + 2 * tid);
    x3[0][tid] = as_u32(pkf16(a.x, a.y));
    x3[1][tid] = as_u32(pkf16(c.x, c.y));
  }
  __syncthreads();

  if (wid < 8) {
    // ================= group A: layer 0, step t = i =================
    const int c = wid * 16 + cl;
    h8 wh[4], wx[2], wt[2];
    {
      const float* p = Wh0 + c * H_ + (l >> 4) * 8;
      #pragma unroll
      for (int kk = 0; kk < 4; ++kk) wh[kk] = packfrag(p + kk * 32);
      const float* q = Wx0 + c * F_ + (l >> 4) * 8;
      wx[0] = packfrag(q); wx[1] = packfrag(q + 32);
      const float* r = Wt0 + c * F_ + (l >> 4) * 8;
      wt[0] = packfrag(r); wt[1] = packfrag(r + 32);
    }
    const float bhx = bh0[c] + bx0[c];
    const float btr = bt0[c], taub = tau0[c], gr = g0[c], ber = be0[c];
    const int  widx = wid * 8 + (cl >> 1);
    const bool st = (wid == 0) && (l < 32);

    float hold = 0.f;
    float2 xcur;                     // x[i+2], loaded one step early
    if (st) xcur = *(const float2*)(xg + 2 * F_ + 2 * l);
    int c0 = 0, cw = 2;              // read buf i%3, write buf (i+2)%3

    for (int i = 0; i <= T_; ++i) {
      if (st) {                      // write x[i+2]; issue load of x[i+3]
        x3[cw][l] = as_u32(pkf16(xcur.x, xcur.y));
        int tn = i + 3; if (tn > T_ - 1) tn = T_ - 1;
        xcur = *(const float2*)(xg + tn * F_ + 2 * l);
      }
      const uint32_t* hb = h0p[i & 1];              // h0[i-1]
      f32x4 aA = {0.f,0.f,0.f,0.f}, aB = {0.f,0.f,0.f,0.f}, aT = {0.f,0.f,0.f,0.f};
      #pragma unroll
      for (int kk = 0; kk < 4; ++kk)
        aA = __builtin_amdgcn_mfma_f32_16x16x32_f16(ldfrag(hb + kk * 16 + g4), wh[kk], aA, 0, 0, 0);
      const uint32_t* xb = x3[c0];                  // x[i]
      #pragma unroll
      for (int kk = 0; kk < 2; ++kk) {
        h8 xf = ldfrag(xb + kk * 16 + g4);
        aB = __builtin_amdgcn_mfma_f32_16x16x32_f16(xf, wx[kk], aB, 0, 0, 0);
        aT = __builtin_amdgcn_mfma_f32_16x16x32_f16(xf, wt[kk], aT, 0, 0, 0);
      }
      float pa = aA[0] + aB[0], pt = aT[0];
      hold = ln_tail2(pa, pt, hold, bhx, btr, taub, gr, ber,
                      l, wid, part, 0, h0p[(i + 1) & 1], widx, true);
      c0 = (c0 == 2) ? 0 : c0 + 1;
      cw = (cw == 2) ? 0 : cw + 1;
    }
  } else {
    // ================= group B: layer 1, step t = i-1 =================
    const int c = (wid - 8) * 16 + cl;
    h8 vh[4], vx[4], vt[4];
    {
      const float* p = Wh1 + c * H_ + (l >> 4) * 8;
      const float* q = Wx1 + c * H_ + (l >> 4) * 8;
      const float* r = Wt1 + c * H_ + (l >> 4) * 8;
      #pragma unroll
      for (int kk = 0; kk < 4; ++kk) {
        vh[kk] = packfrag(p + kk * 32);
        vx[kk] = packfrag(q + kk * 32);
        vt[kk] = packfrag(r + kk * 32);
      }
    }
    const float bhx = bh1[c] + bx1[c];
    const float btr = bt1[c], taub = tau1[c], gr = g1[c], ber = be1[c];
    const int  widx = (wid - 8) * 8 + (cl >> 1);

    float hold = 0.f;
    for (int i = 0; i <= T_; ++i) {
      const uint32_t* hb = h0p[i & 1];              // h0[i-1]
      f32x4 aA = {0.f,0.f,0.f,0.f}, aB = {0.f,0.f,0.f,0.f}, aT = {0.f,0.f,0.f,0.f};
      #pragma unroll
      for (int kk = 0; kk < 4; ++kk) {
        h8 h1f = ldfrag(h1p + kk * 16 + g4);        // h1[i-2]
        h8 h0f = ldfrag(hb  + kk * 16 + g4);
        aA = __builtin_amdgcn_mfma_f32_16x16x32_f16(h1f, vh[kk], aA, 0, 0, 0);
        aB = __builtin_amdgcn_mfma_f32_16x16x32_f16(h0f, vx[kk], aB, 0, 0, 0);
        aT = __builtin_amdgcn_mfma_f32_16x16x32_f16(h0f, vt[kk], aT, 0, 0, 0);
      }
      float pa = aA[0] + aB[0], pt = aT[0];
      float hn = ln_tail2(pa, pt, hold, bhx, btr, taub, gr, ber,
                          l, wid, part, 8, h1p, widx, i > 0);
      if (i > 0) hold = hn;
    }
    if ((l & 48) == 0) out[b * H_ + c] = hold;      // h1[T-1], lanes g==0
  }
}

extern "C" void kernel_launch(void* const* d_in, const int* in_sizes, int n_in,
                              void* d_out, int out_size, void* d_ws, size_t ws_size,
                              hipStream_t stream) {
  const float* x    = (const float*)d_in[0];
  const float* Wh0  = (const float*)d_in[1];
  const float* bh0  = (const float*)d_in[2];
  const float* Wx0  = (const float*)d_in[3];
  const float* bx0  = (const float*)d_in[4];
  const float* Wt0  = (const float*)d_in[5];
  const float* bt0  = (const float*)d_in[6];
  const float* tau0 = (const float*)d_in[7];
  const float* g0   = (const float*)d_in[8];
  const float* be0  = (const float*)d_in[9];
  const float* Wh1  = (const float*)d_in[10];
  const float* bh1  = (const float*)d_in[11];
  const float* Wx1  = (const float*)d_in[12];
  const float* bx1  = (const float*)d_in[13];
  const float* Wt1  = (const float*)d_in[14];
  const float* bt1  = (const float*)d_in[15];
  const float* tau1 = (const float*)d_in[16];
  const float* g1   = (const float*)d_in[17];
  const float* be1  = (const float*)d_in[18];
  float* out        = (float*)d_out;

  ltc_scan<<<B_, NT_, 0, stream>>>(x, Wh0, bh0, Wx0, bx0, Wt0, bt0, tau0, g0, be0,
                                   Wh1, bh1, Wx1, bx1, Wt1, bt1, tau1, g1, be1, out);
}